// Round 1
// baseline (212.586 us; speedup 1.0000x reference)
//
#include <hip/hip_runtime.h>
#include <math.h>

#define N_PTS 1000000
#define H_IMG 480
#define W_IMG 640
#define PIX (H_IMG * W_IMG)

// One Jacobi rotation annihilating M[p][q]; updates M (full symmetric) and V columns.
#define ROT(p, q)                                                              \
  do {                                                                         \
    double apq = Mv[p][q];                                                     \
    if (apq != 0.0) {                                                          \
      double app = Mv[p][p], aqq = Mv[q][q];                                   \
      double th = (aqq - app) / (2.0 * apq);                                   \
      double t = 1.0 / (fabs(th) + sqrt(1.0 + th * th));                       \
      if (th < 0.0) t = -t;                                                    \
      double c = 1.0 / sqrt(1.0 + t * t);                                      \
      double s = t * c;                                                        \
      Mv[p][p] = app - t * apq;                                                \
      Mv[q][q] = aqq + t * apq;                                                \
      Mv[p][q] = 0.0;                                                          \
      Mv[q][p] = 0.0;                                                          \
      _Pragma("unroll") for (int k = 0; k < 4; k++) {                          \
        if (k != p && k != q) {                                                \
          double akp = Mv[k][p], akq = Mv[k][q];                               \
          double nkp = c * akp - s * akq;                                      \
          double nkq = s * akp + c * akq;                                      \
          Mv[k][p] = nkp; Mv[p][k] = nkp;                                      \
          Mv[k][q] = nkq; Mv[q][k] = nkq;                                      \
        }                                                                      \
      }                                                                        \
      _Pragma("unroll") for (int k = 0; k < 4; k++) {                          \
        double vkp = Vv[k][p], vkq = Vv[k][q];                                 \
        Vv[k][p] = c * vkp - s * vkq;                                          \
        Vv[k][q] = s * vkp + c * vkq;                                          \
      }                                                                        \
    }                                                                          \
  } while (0)

__global__ __launch_bounds__(256) void tri_main(
    const float* __restrict__ T,     // 16
    const float* __restrict__ K0,    // 9
    const float* __restrict__ K1,    // 9
    const float* __restrict__ mconf, // N
    const float* __restrict__ kp0,   // N*2
    const float* __restrict__ kp1,   // N*2
    float* __restrict__ out_kp3d,    // N (d_out + PIX)
    unsigned long long* __restrict__ ws_pix) // PIX packed (n<<32)|bits(kp)
{
  int n = blockIdx.x * blockDim.x + threadIdx.x;
  if (n >= N_PTS) return;

  float2 p0 = ((const float2*)kp0)[n];
  float2 p1 = ((const float2*)kp1)[n];
  double conf = (double)mconf[n];
  double x0 = (double)p0.x, y0 = (double)p0.y;
  double x1 = (double)p1.x, y1 = (double)p1.y;

  // P0 = K0 @ [I|0]
  double P0[3][4];
#pragma unroll
  for (int i = 0; i < 3; i++) {
#pragma unroll
    for (int j = 0; j < 3; j++) P0[i][j] = (double)K0[i * 3 + j];
    P0[i][3] = 0.0;
  }
  // P1 = K1 @ T[:3,:]
  double P1[3][4];
#pragma unroll
  for (int i = 0; i < 3; i++) {
#pragma unroll
    for (int j = 0; j < 4; j++) {
      double s = 0.0;
#pragma unroll
      for (int k = 0; k < 3; k++)
        s += (double)K1[i * 3 + k] * (double)T[k * 4 + j];
      P1[i][j] = s;
    }
  }

  // M = A^T A accumulated row-by-row (rows of A never all live at once)
  double Mv[4][4];
#pragma unroll
  for (int i = 0; i < 4; i++)
#pragma unroll
    for (int j = 0; j < 4; j++) Mv[i][j] = 0.0;

  double a[4];
#pragma unroll
  for (int j = 0; j < 4; j++) a[j] = x0 * P0[2][j] - P0[0][j];
#pragma unroll
  for (int i = 0; i < 4; i++)
#pragma unroll
    for (int j = 0; j < 4; j++) Mv[i][j] += a[i] * a[j];

#pragma unroll
  for (int j = 0; j < 4; j++) a[j] = y0 * P0[2][j] - P0[1][j];
#pragma unroll
  for (int i = 0; i < 4; i++)
#pragma unroll
    for (int j = 0; j < 4; j++) Mv[i][j] += a[i] * a[j];

#pragma unroll
  for (int j = 0; j < 4; j++) a[j] = conf * (x1 * P1[2][j] - P1[0][j]);
#pragma unroll
  for (int i = 0; i < 4; i++)
#pragma unroll
    for (int j = 0; j < 4; j++) Mv[i][j] += a[i] * a[j];

#pragma unroll
  for (int j = 0; j < 4; j++) a[j] = conf * (y1 * P1[2][j] - P1[1][j]);
#pragma unroll
  for (int i = 0; i < 4; i++)
#pragma unroll
    for (int j = 0; j < 4; j++) Mv[i][j] += a[i] * a[j];

  // Jacobi eigensolve: V accumulates eigenvectors (columns)
  double Vv[4][4];
#pragma unroll
  for (int i = 0; i < 4; i++)
#pragma unroll
    for (int j = 0; j < 4; j++) Vv[i][j] = (i == j) ? 1.0 : 0.0;

  for (int sweep = 0; sweep < 6; sweep++) {
    ROT(0, 1);
    ROT(0, 2);
    ROT(0, 3);
    ROT(1, 2);
    ROT(1, 3);
    ROT(2, 3);
  }

  // Branchless pick of eigenvector with smallest eigenvalue; only rows 2,3 needed
  double e0 = Mv[0][0], e1 = Mv[1][1], e2 = Mv[2][2], e3 = Mv[3][3];
  bool b01 = e1 < e0;
  double ea = b01 ? e1 : e0;
  double za = b01 ? Vv[2][1] : Vv[2][0];
  double wa = b01 ? Vv[3][1] : Vv[3][0];
  bool b23 = e3 < e2;
  double eb = b23 ? e3 : e2;
  double zb = b23 ? Vv[2][3] : Vv[2][2];
  double wb = b23 ? Vv[3][3] : Vv[3][2];
  bool bf = eb < ea;
  double vz = bf ? zb : za;
  double vw = bf ? wb : wa;

  // z = clip(clip(vz/vw, -1000, 1000), 0, 30) == clip(vz/vw, 0, 30)
  double z = vz / vw;
  z = fmin(fmax(z, 0.0), 30.0);
  bool filt = (z > 0.0) && (z < 30.0);
  float kp = filt ? (float)z : 0.0f;

  out_kp3d[n] = kp;

  // last-write-wins scatter: max point index wins per pixel
  int xi = (int)p0.x;
  int yi = (int)p0.y;
  int pix = yi * W_IMG + xi;
  unsigned long long packed =
      ((unsigned long long)(unsigned)n << 32) |
      (unsigned long long)__float_as_uint(kp);
  atomicMax(&ws_pix[pix], packed);
}

__global__ __launch_bounds__(256) void unpack_depth(
    const unsigned long long* __restrict__ ws_pix,
    float* __restrict__ out_depth)
{
  int p = blockIdx.x * blockDim.x + threadIdx.x;
  if (p < PIX)
    out_depth[p] = __uint_as_float((unsigned)(ws_pix[p] & 0xffffffffULL));
}

extern "C" void kernel_launch(void* const* d_in, const int* in_sizes, int n_in,
                              void* d_out, int out_size, void* d_ws, size_t ws_size,
                              hipStream_t stream) {
  const float* T     = (const float*)d_in[0]; // T_0to1 [1,4,4]
  const float* K0    = (const float*)d_in[1]; // [1,3,3]
  const float* K1    = (const float*)d_in[2]; // [1,3,3]
  const float* mconf = (const float*)d_in[3]; // [N]
  const float* kp0   = (const float*)d_in[4]; // [N,2]
  const float* kp1   = (const float*)d_in[5]; // [N,2]
  // d_in[6] image0 (shape only), d_in[7] m_bids (all zero) — unused

  float* out = (float*)d_out; // [PIX depth plane][N kp3d]
  unsigned long long* ws = (unsigned long long*)d_ws; // PIX u64

  hipMemsetAsync(d_ws, 0, (size_t)PIX * sizeof(unsigned long long), stream);

  tri_main<<<(N_PTS + 255) / 256, 256, 0, stream>>>(
      T, K0, K1, mconf, kp0, kp1, out + PIX, ws);

  unpack_depth<<<(PIX + 255) / 256, 256, 0, stream>>>(ws, out);
}

// Round 2
// 148.271 us; speedup vs baseline: 1.4338x; 1.4338x over previous
//
#include <hip/hip_runtime.h>
#include <math.h>

#define N_PTS 1000000
#define H_IMG 480
#define W_IMG 640
#define PIX (H_IMG * W_IMG)

// Jacobi rotation zeroing M[p][q].
// t = 2*apq*sign(d)/(|d|+r) with r = sqrt(d^2+4 apq^2)  (identical to the
// classic th->t formula but 1 sqrt + 1 div + 1 rsqrt instead of 3 div + 2 sqrt).
// Only rows 2,3 of the eigenvector matrix are tracked (all we ever read).
#define ROT(p, q)                                                              \
  do {                                                                         \
    double apq = Mv[p][q];                                                     \
    if (apq != 0.0) {                                                          \
      double app = Mv[p][p], aqq = Mv[q][q];                                   \
      double d = aqq - app;                                                    \
      double r = sqrt(fma(d, d, 4.0 * apq * apq));                             \
      double t = (2.0 * apq) / (d + copysign(r, d));                           \
      double c = rsqrt(fma(t, t, 1.0));                                        \
      double s = t * c;                                                        \
      Mv[p][p] = fma(-t, apq, app);                                            \
      Mv[q][q] = fma(t, apq, aqq);                                             \
      Mv[p][q] = 0.0;                                                          \
      Mv[q][p] = 0.0;                                                          \
      _Pragma("unroll") for (int k = 0; k < 4; k++) {                          \
        if (k != p && k != q) {                                                \
          double akp = Mv[k][p], akq = Mv[k][q];                               \
          double nkp = c * akp - s * akq;                                      \
          double nkq = s * akp + c * akq;                                      \
          Mv[k][p] = nkp; Mv[p][k] = nkp;                                      \
          Mv[k][q] = nkq; Mv[q][k] = nkq;                                      \
        }                                                                      \
      }                                                                        \
      { double v2p = Vr2[p], v2q = Vr2[q];                                     \
        Vr2[p] = c * v2p - s * v2q; Vr2[q] = s * v2p + c * v2q; }              \
      { double v3p = Vr3[p], v3q = Vr3[q];                                     \
        Vr3[p] = c * v3p - s * v3q; Vr3[q] = s * v3p + c * v3q; }              \
    }                                                                          \
  } while (0)

__global__ __launch_bounds__(256) void tri_main(
    const float* __restrict__ T,     // 16
    const float* __restrict__ K0,    // 9
    const float* __restrict__ K1,    // 9
    const float* __restrict__ mconf, // N
    const float* __restrict__ kp0,   // N*2
    const float* __restrict__ kp1,   // N*2
    float* __restrict__ out_kp3d,    // N (d_out + PIX)
    unsigned long long* __restrict__ ws_pix) // PIX packed (n<<32)|bits(kp)
{
  int n = blockIdx.x * blockDim.x + threadIdx.x;
  if (n >= N_PTS) return;

  float2 p0 = ((const float2*)kp0)[n];
  float2 p1 = ((const float2*)kp1)[n];
  double conf = (double)mconf[n];
  double x0 = (double)p0.x, y0 = (double)p0.y;
  double x1 = (double)p1.x, y1 = (double)p1.y;

  // P0 = K0 @ [I|0]
  double P0[3][4];
#pragma unroll
  for (int i = 0; i < 3; i++) {
#pragma unroll
    for (int j = 0; j < 3; j++) P0[i][j] = (double)K0[i * 3 + j];
    P0[i][3] = 0.0;
  }
  // P1 = K1 @ T[:3,:]
  double P1[3][4];
#pragma unroll
  for (int i = 0; i < 3; i++) {
#pragma unroll
    for (int j = 0; j < 4; j++) {
      double s = 0.0;
#pragma unroll
      for (int k = 0; k < 3; k++)
        s += (double)K1[i * 3 + k] * (double)T[k * 4 + j];
      P1[i][j] = s;
    }
  }

  // M = A^T A accumulated row-by-row
  double Mv[4][4];
#pragma unroll
  for (int i = 0; i < 4; i++)
#pragma unroll
    for (int j = 0; j < 4; j++) Mv[i][j] = 0.0;

  double a[4];
#pragma unroll
  for (int j = 0; j < 4; j++) a[j] = x0 * P0[2][j] - P0[0][j];
#pragma unroll
  for (int i = 0; i < 4; i++)
#pragma unroll
    for (int j = 0; j < 4; j++) Mv[i][j] = fma(a[i], a[j], Mv[i][j]);

#pragma unroll
  for (int j = 0; j < 4; j++) a[j] = y0 * P0[2][j] - P0[1][j];
#pragma unroll
  for (int i = 0; i < 4; i++)
#pragma unroll
    for (int j = 0; j < 4; j++) Mv[i][j] = fma(a[i], a[j], Mv[i][j]);

#pragma unroll
  for (int j = 0; j < 4; j++) a[j] = conf * (x1 * P1[2][j] - P1[0][j]);
#pragma unroll
  for (int i = 0; i < 4; i++)
#pragma unroll
    for (int j = 0; j < 4; j++) Mv[i][j] = fma(a[i], a[j], Mv[i][j]);

#pragma unroll
  for (int j = 0; j < 4; j++) a[j] = conf * (y1 * P1[2][j] - P1[1][j]);
#pragma unroll
  for (int i = 0; i < 4; i++)
#pragma unroll
    for (int j = 0; j < 4; j++) Mv[i][j] = fma(a[i], a[j], Mv[i][j]);

  // Eigenvector rows 2,3 only
  double Vr2[4] = {0.0, 0.0, 1.0, 0.0};
  double Vr3[4] = {0.0, 0.0, 0.0, 1.0};

  // 4 cyclic sweeps: quadratic convergence puts off-diag ~machine eps,
  // far below the reference's own fp32-SVD noise floor (absmax 0.125).
  for (int sweep = 0; sweep < 4; sweep++) {
    ROT(0, 1);
    ROT(0, 2);
    ROT(0, 3);
    ROT(1, 2);
    ROT(1, 3);
    ROT(2, 3);
  }

  // Branchless pick of eigenvector with smallest eigenvalue
  double e0 = Mv[0][0], e1 = Mv[1][1], e2 = Mv[2][2], e3 = Mv[3][3];
  bool b01 = e1 < e0;
  double ea = b01 ? e1 : e0;
  double za = b01 ? Vr2[1] : Vr2[0];
  double wa = b01 ? Vr3[1] : Vr3[0];
  bool b23 = e3 < e2;
  double eb = b23 ? e3 : e2;
  double zb = b23 ? Vr2[3] : Vr2[2];
  double wb = b23 ? Vr3[3] : Vr3[2];
  bool bf = eb < ea;
  double vz = bf ? zb : za;
  double vw = bf ? wb : wa;

  // z = clip(vz/vw, 0, 30); filter open interval
  double z = vz / vw;
  z = fmin(fmax(z, 0.0), 30.0);
  bool filt = (z > 0.0) && (z < 30.0);
  float kp = filt ? (float)z : 0.0f;

  out_kp3d[n] = kp;

  // last-write-wins scatter: max point index wins per pixel
  int xi = (int)p0.x;
  int yi = (int)p0.y;
  int pix = yi * W_IMG + xi;
  unsigned long long packed =
      ((unsigned long long)(unsigned)n << 32) |
      (unsigned long long)__float_as_uint(kp);
  atomicMax(&ws_pix[pix], packed);
}

__global__ __launch_bounds__(256) void unpack_depth(
    const unsigned long long* __restrict__ ws_pix,
    float* __restrict__ out_depth)
{
  int p = blockIdx.x * blockDim.x + threadIdx.x;
  if (p < PIX)
    out_depth[p] = __uint_as_float((unsigned)(ws_pix[p] & 0xffffffffULL));
}

extern "C" void kernel_launch(void* const* d_in, const int* in_sizes, int n_in,
                              void* d_out, int out_size, void* d_ws, size_t ws_size,
                              hipStream_t stream) {
  const float* T     = (const float*)d_in[0]; // T_0to1 [1,4,4]
  const float* K0    = (const float*)d_in[1]; // [1,3,3]
  const float* K1    = (const float*)d_in[2]; // [1,3,3]
  const float* mconf = (const float*)d_in[3]; // [N]
  const float* kp0   = (const float*)d_in[4]; // [N,2]
  const float* kp1   = (const float*)d_in[5]; // [N,2]
  // d_in[6] image0 (shape only), d_in[7] m_bids (all zero) — unused

  float* out = (float*)d_out; // [PIX depth plane][N kp3d]
  unsigned long long* ws = (unsigned long long*)d_ws; // PIX u64

  hipMemsetAsync(d_ws, 0, (size_t)PIX * sizeof(unsigned long long), stream);

  tri_main<<<(N_PTS + 255) / 256, 256, 0, stream>>>(
      T, K0, K1, mconf, kp0, kp1, out + PIX, ws);

  unpack_depth<<<(PIX + 255) / 256, 256, 0, stream>>>(ws, out);
}